// Round 17
// baseline (221.678 us; speedup 1.0000x reference)
//
#include <hip/hip_runtime.h>

// ---------------------------------------------------------------------------
// AttentionMultiHead: x[8,1024,1024] f32, per-head Wq/Wk/Wv[16,1024,64]+bias,
// Wo[1024,64]+bo. Outputs: z_out[8,1024,64] f32, att[8,16,1024,1024] f32 (raw).
//
// Ledger after R16 (218.1us, best): attn ~120 (5.1 TB/s eff, fill ceiling
// 6.7), gemm ~50, pack ~19, out ~8, gaps ~15. Confirmed: request-rate
// coalescing (R11/R12/R16), nt no-pollution (R7/R13), 128-kv single-buffer
// attn groups (R14/R15), BK=64 + chunk-XOR LDS (R16).
// R17: (1) attn q-tile 64->128 (8 waves/block, 1024 blocks): staged K/V
// traffic and barrier-drain count halve; LDS 62KB -> 2 blocks/CU = 16
// waves/CU. Per-wave code identical. (2) gemm_out: 512 blocks, 16-row
// m-tiles, 4-way K-split + LDS reduce (was 1 block/CU, 2-way).
// ---------------------------------------------------------------------------

typedef __bf16 bf16x8 __attribute__((ext_vector_type(8)));
typedef float f32x4 __attribute__((ext_vector_type(4)));
typedef unsigned short u16x8 __attribute__((ext_vector_type(8)));
typedef unsigned short u16x4 __attribute__((ext_vector_type(4)));

typedef __attribute__((address_space(1))) unsigned int as1_u32;
typedef __attribute__((address_space(3))) unsigned int as3_u32;

#define MFMA16(a, b, c) __builtin_amdgcn_mfma_f32_16x16x32_bf16(a, b, c, 0, 0, 0)

__device__ __forceinline__ void gload_lds16(const void* g, void* l) {
  __builtin_amdgcn_global_load_lds((const as1_u32*)g, (as3_u32*)l, 16, 0, 0);
}

__device__ __forceinline__ unsigned short f2bf(float f) {
  union { float f; unsigned u; } a; a.f = f;
  unsigned r = a.u + 0x7FFFu + ((a.u >> 16) & 1u);  // RNE
  return (unsigned short)(r >> 16);
}

// ---------------- fused pack kernel ----------------
// blocks [0,8192): x->bf16 (float4 copy); [8192,8960): W transpose via LDS
// tile (coalesced float4 reads, u16x8 writes); [8960,9229): Wop + bqkv.
__global__ __launch_bounds__(256) void pack_all(const float* __restrict__ x, const float* __restrict__ Wq,
                                                const float* __restrict__ Wk, const float* __restrict__ Wv,
                                                const float* __restrict__ Wo, const float* __restrict__ bq,
                                                const float* __restrict__ bk, const float* __restrict__ bv,
                                                ushort* __restrict__ xb, ushort* __restrict__ Wp,
                                                ushort* __restrict__ Wop, float* __restrict__ bqkv) {
  __shared__ float tile[64][65];   // 65-pad: transpose col reads <=2-way (free)
  const int bid = blockIdx.x;
  if (bid < 8192) {
    const size_t i = ((size_t)bid * 256 + threadIdx.x) * 4;
    const float4 v = *(const float4*)(x + i);
    u16x4 o; o[0] = f2bf(v.x); o[1] = f2bf(v.y); o[2] = f2bf(v.z); o[3] = f2bf(v.w);
    *(u16x4*)(xb + i) = o;
  } else if (bid < 8960) {
    // one block per (proj, h, dtile): transpose W[h][d0..d0+64][0..64]
    const int b3 = bid - 8192;
    const int proj = b3 >> 8, rem = b3 & 255;
    const int h = rem >> 4, dt = rem & 15;
    const float* W = proj == 0 ? Wq : (proj == 1 ? Wk : Wv);
    const int r = threadIdx.x >> 2, cc = (threadIdx.x & 3) * 16;
    const float* src = W + ((size_t)h * 1024 + dt * 64 + r) * 64 + cc;
#pragma unroll
    for (int i = 0; i < 4; ++i) {
      const float4 v = *(const float4*)(src + i * 4);
      tile[r][cc + i * 4 + 0] = v.x; tile[r][cc + i * 4 + 1] = v.y;
      tile[r][cc + i * 4 + 2] = v.z; tile[r][cc + i * 4 + 3] = v.w;
    }
    __syncthreads();
    const int kk = threadIdx.x >> 2, dc = (threadIdx.x & 3) * 16;
    u16x8 o0, o1;
#pragma unroll
    for (int i = 0; i < 8; ++i) o0[i] = f2bf(tile[dc + i][kk]);
#pragma unroll
    for (int i = 0; i < 8; ++i) o1[i] = f2bf(tile[dc + 8 + i][kk]);
    ushort* dst = Wp + (size_t)(proj * 1024 + h * 64 + kk) * 1024 + dt * 64 + dc;
    *(u16x8*)dst = o0;
    *(u16x8*)(dst + 8) = o1;
  } else {
    const int idx = (bid - 8960) * 256 + threadIdx.x;
    if (idx < 65536) {
      const int n = idx >> 10, c = idx & 1023;   // Wop[n][c] = Wo[c][n]
      Wop[idx] = f2bf(Wo[c * 64 + n]);
    } else if (idx < 65536 + 3072) {
      const int n = idx - 65536;
      const int proj = n >> 10;
      const float* bb = proj == 0 ? bq : (proj == 1 ? bk : bv);
      bqkv[n] = bb[n & 1023];
    }
  }
}

// ---------------- QKV projection GEMM (BK=64, chunk-XOR swizzled LDS) -------
__global__ __launch_bounds__(256) void gemm_qkv(const ushort* __restrict__ xb, const ushort* __restrict__ Wp,
                                                const float* __restrict__ bqkv, ushort* __restrict__ qo,
                                                ushort* __restrict__ ko, ushort* __restrict__ vTo) {
  __shared__ ushort As[128 * 64], Bs[128 * 64];   // 32 KB
  const int bid = blockIdx.x;                 // 1536 blocks
  const int xcd = bid & 7, idx = bid >> 3;
  const int bx = idx >> 3, by = xcd * 8 + (idx & 7);
  const int t = threadIdx.x, w = t >> 6, l = t & 63, lg = l >> 4, lr = l & 15;
  const int m0 = by * 128, n0 = bx * 128;
  const int wm = w >> 1, wn = w & 1;
  const int r8 = l >> 3, ch = l & 7;          // staging lane geometry
  f32x4 acc[4][4] = {};
  for (int kt = 0; kt < 16; ++kt) {
    __syncthreads();
#pragma unroll
    for (int c2 = 0; c2 < 4; ++c2) {
      const int c = w * 4 + c2;               // chunk 0..15 (8 rows x 128B)
      const int row = c * 8 + r8;             // 0..127
      const int sc = (ch ^ (row & 7)) * 8;    // pre-swizzled source col
      gload_lds16(xb + (size_t)(m0 + row) * 1024 + kt * 64 + sc, &As[c * 512]);
      gload_lds16(Wp + (size_t)(n0 + row) * 1024 + kt * 64 + sc, &Bs[c * 512]);
    }
    __syncthreads();
#pragma unroll
    for (int hk = 0; hk < 2; ++hk) {          // two K=32 halves of the 64-tile
      bf16x8 af[4], bfr[4];
#pragma unroll
      for (int mt = 0; mt < 4; ++mt) {
        const int row = wm * 64 + mt * 16 + lr;
        af[mt] = *(const bf16x8*)(&As[row * 64 + (((hk * 4 + lg) ^ (row & 7)) * 8)]);
      }
#pragma unroll
      for (int nt = 0; nt < 4; ++nt) {
        const int row = wn * 64 + nt * 16 + lr;
        bfr[nt] = *(const bf16x8*)(&Bs[row * 64 + (((hk * 4 + lg) ^ (row & 7)) * 8)]);
      }
#pragma unroll
      for (int mt = 0; mt < 4; ++mt)
#pragma unroll
        for (int nt = 0; nt < 4; ++nt)
          acc[mt][nt] = MFMA16(af[mt], bfr[nt], acc[mt][nt]);
    }
  }
  // epilogue: bias + relu -> bf16. proj uniform across the wave (16-aligned n-chunks).
#pragma unroll
  for (int nt = 0; nt < 4; ++nt) {
    const int n = n0 + wn * 64 + nt * 16 + lr;
    const float bias = bqkv[n];
    const int proj = n >> 10, h = (n >> 6) & 15, dk = n & 63;
#pragma unroll
    for (int mt = 0; mt < 4; ++mt) {
      const int mb = m0 + wm * 64 + mt * 16 + lg * 4;  // j-quad base, same b & 4-aligned s
      const int b = mb >> 10, s = mb & 1023;
      float vv[4];
#pragma unroll
      for (int j = 0; j < 4; ++j) {
        float a = acc[mt][nt][j] + bias;
        vv[j] = a > 0.f ? a : 0.f;
      }
      if (proj == 2) {
        u16x4 o; o[0] = f2bf(vv[0]); o[1] = f2bf(vv[1]); o[2] = f2bf(vv[2]); o[3] = f2bf(vv[3]);
        *(u16x4*)(vTo + ((size_t)(b * 16 + h) * 64 + dk) * 1024 + s) = o;
      } else {
        ushort* op = proj == 0 ? qo : ko;
#pragma unroll
        for (int j = 0; j < 4; ++j)
          op[((size_t)(b * 16 + h) * 1024 + s + j) * 64 + dk] = f2bf(vv[j]);
      }
    }
  }
}

// ---------------- fused attention (128-row q-tiles, 8 waves/block) ----------
// 1024 blocks (XCD-swizzled: each XCD owns 16 bh x all 8 q-tiles; 4MB K/vT
// working set = one L2). Per 128-kv group: stage K,V once per block (shared
// by 8 waves - staged traffic halved vs 64-row blocks); QK^T (swapped);
// 4 s-slices of 32 kv {exp->p_q + scores->s_st; lgkmcnt; NT full-128B-line
// flush; PV}. Per-wave code identical to R16.
__global__ __launch_bounds__(512) void attn_kernel(const ushort* __restrict__ qg, const ushort* __restrict__ kg,
                                                   const ushort* __restrict__ vT, float* __restrict__ att,
                                                   ushort* __restrict__ heads) {
  const int bid = blockIdx.x;                 // 1024
  const int swz = (bid & 7) * 128 + (bid >> 3);
  const int qt = swz & 7, bh = swz >> 3;
  const int t = threadIdx.x, w = t >> 6, l = t & 63;
  const int lg = l >> 4, lr = l & 15;
  __shared__ ushort Ks[128 * 64];         // 16 KB, chunk-swizzled rows
  __shared__ ushort Vs[64 * 128];         // 16 KB, chunk-swizzled rows
  __shared__ ushort p_q[8][16][40];       // 10 KB, P quarter (32 kv), reused
  __shared__ float s_st[8][16][40];       // 20 KB, score quarter (32 kv), reused

  const ushort* qb = qg + (size_t)bh * 65536;
  const ushort* kb = kg + (size_t)bh * 65536;
  const ushort* vb = vT + (size_t)bh * 65536;
  const int qrow0 = qt * 128 + w * 16;

  const bf16x8 qf0 = *(const bf16x8*)(qb + (qrow0 + lr) * 64 + lg * 8);
  const bf16x8 qf1 = *(const bf16x8*)(qb + (qrow0 + lr) * 64 + 32 + lg * 8);

  const int krow = l >> 3, kch = l & 7;    // K: 8 rows x 8 chunks(16B)
  const int vrow = l >> 4, vch = l & 15;   // V: 4 rows x 16 chunks(16B)
  const int frow = l >> 3, fcol = (l & 7) * 4;  // flush: 8 rows x 128B per instr

  const float C2 = 0.125f * 1.44269504f;   // 1/sqrt(64) in exp2 domain
  f32x4 oacc[4] = {};
  float lsum = 0.f;
  float* attw = att + ((size_t)bh * 1024 + qrow0) * 1024;

  for (int g = 0; g < 8; ++g) {
    const int kv0 = g * 128;
    __syncthreads();   // all waves done reading previous group's tiles
#pragma unroll
    for (int c2 = 0; c2 < 2; ++c2) {
      const int call = w * 2 + c2;         // 16 calls across 8 waves
      const int r = call * 8 + krow;       // K local row 0..127
      gload_lds16(kb + (size_t)(kv0 + r) * 64 + ((kch ^ (r & 7)) * 8), &Ks[call * 512]);
      const int rv = call * 4 + vrow;      // V local row (dk) 0..63
      gload_lds16(vb + (size_t)rv * 1024 + kv0 + ((vch ^ (rv & 15)) * 8), &Vs[call * 512]);
    }
    __syncthreads();   // stage complete
    // QK^T from LDS: sf[f][j] = S[q=lr][kv = kv0 + f*16 + lg*4 + j]
    f32x4 sf[8];
#pragma unroll
    for (int f = 0; f < 8; ++f) {
      const int r = f * 16 + lr;
      const bf16x8 kf0 = *(const bf16x8*)(&Ks[r * 64 + ((lg ^ (r & 7)) * 8)]);
      const bf16x8 kf1 = *(const bf16x8*)(&Ks[r * 64 + (((4 + lg) ^ (r & 7)) * 8)]);
      f32x4 s = {};
      s = MFMA16(kf0, qf0, s);
      s = MFMA16(kf1, qf1, s);
      sf[f] = s;
    }
    // 4 slices of 32 kv: exp/pack + score-stage -> nt line flush + PV
#pragma unroll
    for (int s = 0; s < 4; ++s) {
#pragma unroll
      for (int fi = 0; fi < 2; ++fi) {
        const int f = 2 * s + fi;
        u16x4 pk;
#pragma unroll
        for (int j = 0; j < 4; ++j) {
          const float p = exp2f(sf[f][j] * C2);
          lsum += p;
          pk[j] = f2bf(p);
        }
        *(u16x4*)(&p_q[w][lr][fi * 16 + lg * 4]) = pk;
        *(f32x4*)(&s_st[w][lr][fi * 16 + lg * 4]) = sf[f];
      }
      // per-wave LDS region; DS ops wave-program-order; wait for writes
      asm volatile("s_waitcnt lgkmcnt(0)" ::: "memory");
      __builtin_amdgcn_sched_barrier(0);
      const bf16x8 pa = *(const bf16x8*)(&p_q[w][lr][lg * 8]);
      // flush this slice: 2 instrs x 8 rows x 128B fully-covered aligned lines
#pragma unroll
      for (int i = 0; i < 2; ++i) {
        const int r = i * 8 + frow;
        const f32x4 fv = *(const f32x4*)(&s_st[w][r][fcol]);
        __builtin_nontemporal_store(fv,
            (f32x4*)(attw + (size_t)r * 1024 + kv0 + s * 32 + fcol));
      }
      // PV for this slice (LDS/reg only -> store retire shadow)
#pragma unroll
      for (int nt = 0; nt < 4; ++nt) {
        const int r = nt * 16 + lr;
        const bf16x8 vf = *(const bf16x8*)(&Vs[r * 128 + (((s * 4 + lg) ^ lr) * 8)]);
        oacc[nt] = MFMA16(pa, vf, oacc[nt]);
      }
    }
  }
  // row sums: reduce lane partials across lg groups
  lsum += __shfl_xor(lsum, 16, 64);
  lsum += __shfl_xor(lsum, 32, 64);
  float rdiv[4];
#pragma unroll
  for (int j = 0; j < 4; ++j) rdiv[j] = 1.f / __shfl(lsum, lg * 4 + j, 16);
  const int b = bh >> 4, h = bh & 15;
#pragma unroll
  for (int nt = 0; nt < 4; ++nt)
#pragma unroll
    for (int j = 0; j < 4; ++j)
      __builtin_nontemporal_store(f2bf(oacc[nt][j] * rdiv[j]),
          heads + (size_t)(b * 1024 + qrow0 + lg * 4 + j) * 1024 + h * 64 + nt * 16 + lr);
}

// ---------------- output GEMM: z_out = relu(heads @ Wo + bo) ----------------
// 512 blocks x 16-row m-tiles; 4 waves = 4-way K-split (256 K each); LDS
// reduce; wave 0 epilogue. Was 256 blocks / 2-way (1 block/CU, half idle).
__global__ __launch_bounds__(256) void gemm_out(const ushort* __restrict__ z, const ushort* __restrict__ Wop,
                                                const float* __restrict__ bo, float* __restrict__ out) {
  __shared__ float red[4][16][64];
  const int t = threadIdx.x, w = t >> 6, l = t & 63, lg = l >> 4, lr = l & 15;
  const int m0 = blockIdx.x * 16;
  f32x4 acc[4] = {};
  for (int kk = w * 8; kk < w * 8 + 8; ++kk) {
    bf16x8 af = *(const bf16x8*)(z + (size_t)(m0 + lr) * 1024 + kk * 32 + lg * 8);
#pragma unroll
    for (int nt = 0; nt < 4; ++nt) {
      bf16x8 bfr = *(const bf16x8*)(Wop + (size_t)(nt * 16 + lr) * 1024 + kk * 32 + lg * 8);
      acc[nt] = MFMA16(af, bfr, acc[nt]);
    }
  }
  if (w) {
#pragma unroll
    for (int nt = 0; nt < 4; ++nt)
#pragma unroll
      for (int j = 0; j < 4; ++j) red[w][lg * 4 + j][nt * 16 + lr] = acc[nt][j];
  }
  __syncthreads();
  if (w == 0) {
#pragma unroll
    for (int nt = 0; nt < 4; ++nt) {
      const int n = nt * 16 + lr;
      const float bb = bo[n];
#pragma unroll
      for (int j = 0; j < 4; ++j) {
        const int m = lg * 4 + j;
        float vv = acc[nt][j] + red[1][m][n] + red[2][m][n] + red[3][m][n] + bb;
        out[(size_t)(m0 + m) * 64 + n] = vv > 0.f ? vv : 0.f;
      }
    }
  }
}

// ---------------------------------------------------------------------------
extern "C" void kernel_launch(void* const* d_in, const int* in_sizes, int n_in,
                              void* d_out, int out_size, void* d_ws, size_t ws_size,
                              hipStream_t stream) {
  const float* x  = (const float*)d_in[0];
  const float* Wq = (const float*)d_in[1];
  const float* bq = (const float*)d_in[2];
  const float* Wk = (const float*)d_in[3];
  const float* bk = (const float*)d_in[4];
  const float* Wv = (const float*)d_in[5];
  const float* bv = (const float*)d_in[6];
  const float* Wo = (const float*)d_in[7];
  const float* bo = (const float*)d_in[8];
  float* out = (float*)d_out;            // z_out: 8*1024*64 = 524288 f32
  float* att = out + 524288;             // att:   8*16*1024*1024 f32

  // workspace layout (~92 MB)
  char* ws = (char*)d_ws;
  size_t off = 0;
  ushort* xb  = (ushort*)(ws + off); off += (size_t)8192 * 1024 * 2;
  ushort* Wp  = (ushort*)(ws + off); off += (size_t)3072 * 1024 * 2;
  ushort* Wop = (ushort*)(ws + off); off += (size_t)64 * 1024 * 2;
  float* bqkv = (float*)(ws + off);  off += (size_t)3072 * 4;
  ushort* q   = (ushort*)(ws + off); off += (size_t)128 * 1024 * 64 * 2;
  ushort* k   = (ushort*)(ws + off); off += (size_t)128 * 1024 * 64 * 2;
  ushort* vT  = (ushort*)(ws + off); off += (size_t)128 * 64 * 1024 * 2;
  ushort* hds = (ushort*)(ws + off); off += (size_t)8192 * 1024 * 2;
  (void)ws_size; (void)in_sizes; (void)n_in; (void)out_size;

  pack_all<<<dim3(9229), dim3(256), 0, stream>>>(x, Wq, Wk, Wv, Wo, bq, bk, bv,
                                                 xb, Wp, Wop, bqkv);
  gemm_qkv<<<dim3(1536), dim3(256), 0, stream>>>(xb, Wp, bqkv, q, k, vT);
  attn_kernel<<<dim3(1024), dim3(512), 0, stream>>>(q, k, vT, att, hds);
  gemm_out<<<dim3(512), dim3(256), 0, stream>>>(hds, Wop, bo, out);
}

// Round 18
// 218.380 us; speedup vs baseline: 1.0151x; 1.0151x over previous
//
#include <hip/hip_runtime.h>

// ---------------------------------------------------------------------------
// AttentionMultiHead: x[8,1024,1024] f32, per-head Wq/Wk/Wv[16,1024,64]+bias,
// Wo[1024,64]+bo. Outputs: z_out[8,1024,64] f32, att[8,16,1024,1024] f32 (raw).
//
// Ledger: best = R16 218.1us (attn ~120 @64-row/4-wave, gemm ~50 BK=64,
// pack ~19, out ~8, gaps ~15). R17 (+3.5): attn q128/8-wave REGRESSED
// (~+6: wider barrier + 2 blocks/CU < 3 blocks/CU overlap; rhymes with R14) -
// reverted here. gemm_out 512-block/4-way K-split kept (occupancy fix,
// presumed -2..-4; this round isolates it: R18 - R16 = out_change).
// ---------------------------------------------------------------------------

typedef __bf16 bf16x8 __attribute__((ext_vector_type(8)));
typedef float f32x4 __attribute__((ext_vector_type(4)));
typedef unsigned short u16x8 __attribute__((ext_vector_type(8)));
typedef unsigned short u16x4 __attribute__((ext_vector_type(4)));

typedef __attribute__((address_space(1))) unsigned int as1_u32;
typedef __attribute__((address_space(3))) unsigned int as3_u32;

#define MFMA16(a, b, c) __builtin_amdgcn_mfma_f32_16x16x32_bf16(a, b, c, 0, 0, 0)

__device__ __forceinline__ void gload_lds16(const void* g, void* l) {
  __builtin_amdgcn_global_load_lds((const as1_u32*)g, (as3_u32*)l, 16, 0, 0);
}

__device__ __forceinline__ unsigned short f2bf(float f) {
  union { float f; unsigned u; } a; a.f = f;
  unsigned r = a.u + 0x7FFFu + ((a.u >> 16) & 1u);  // RNE
  return (unsigned short)(r >> 16);
}

// ---------------- fused pack kernel ----------------
// blocks [0,8192): x->bf16 (float4 copy); [8192,8960): W transpose via LDS
// tile (coalesced float4 reads, u16x8 writes); [8960,9229): Wop + bqkv.
__global__ __launch_bounds__(256) void pack_all(const float* __restrict__ x, const float* __restrict__ Wq,
                                                const float* __restrict__ Wk, const float* __restrict__ Wv,
                                                const float* __restrict__ Wo, const float* __restrict__ bq,
                                                const float* __restrict__ bk, const float* __restrict__ bv,
                                                ushort* __restrict__ xb, ushort* __restrict__ Wp,
                                                ushort* __restrict__ Wop, float* __restrict__ bqkv) {
  __shared__ float tile[64][65];   // 65-pad: transpose col reads <=2-way (free)
  const int bid = blockIdx.x;
  if (bid < 8192) {
    const size_t i = ((size_t)bid * 256 + threadIdx.x) * 4;
    const float4 v = *(const float4*)(x + i);
    u16x4 o; o[0] = f2bf(v.x); o[1] = f2bf(v.y); o[2] = f2bf(v.z); o[3] = f2bf(v.w);
    *(u16x4*)(xb + i) = o;
  } else if (bid < 8960) {
    // one block per (proj, h, dtile): transpose W[h][d0..d0+64][0..64]
    const int b3 = bid - 8192;
    const int proj = b3 >> 8, rem = b3 & 255;
    const int h = rem >> 4, dt = rem & 15;
    const float* W = proj == 0 ? Wq : (proj == 1 ? Wk : Wv);
    const int r = threadIdx.x >> 2, cc = (threadIdx.x & 3) * 16;
    const float* src = W + ((size_t)h * 1024 + dt * 64 + r) * 64 + cc;
#pragma unroll
    for (int i = 0; i < 4; ++i) {
      const float4 v = *(const float4*)(src + i * 4);
      tile[r][cc + i * 4 + 0] = v.x; tile[r][cc + i * 4 + 1] = v.y;
      tile[r][cc + i * 4 + 2] = v.z; tile[r][cc + i * 4 + 3] = v.w;
    }
    __syncthreads();
    const int kk = threadIdx.x >> 2, dc = (threadIdx.x & 3) * 16;
    u16x8 o0, o1;
#pragma unroll
    for (int i = 0; i < 8; ++i) o0[i] = f2bf(tile[dc + i][kk]);
#pragma unroll
    for (int i = 0; i < 8; ++i) o1[i] = f2bf(tile[dc + 8 + i][kk]);
    ushort* dst = Wp + (size_t)(proj * 1024 + h * 64 + kk) * 1024 + dt * 64 + dc;
    *(u16x8*)dst = o0;
    *(u16x8*)(dst + 8) = o1;
  } else {
    const int idx = (bid - 8960) * 256 + threadIdx.x;
    if (idx < 65536) {
      const int n = idx >> 10, c = idx & 1023;   // Wop[n][c] = Wo[c][n]
      Wop[idx] = f2bf(Wo[c * 64 + n]);
    } else if (idx < 65536 + 3072) {
      const int n = idx - 65536;
      const int proj = n >> 10;
      const float* bb = proj == 0 ? bq : (proj == 1 ? bk : bv);
      bqkv[n] = bb[n & 1023];
    }
  }
}

// ---------------- QKV projection GEMM (BK=64, chunk-XOR swizzled LDS) -------
__global__ __launch_bounds__(256) void gemm_qkv(const ushort* __restrict__ xb, const ushort* __restrict__ Wp,
                                                const float* __restrict__ bqkv, ushort* __restrict__ qo,
                                                ushort* __restrict__ ko, ushort* __restrict__ vTo) {
  __shared__ ushort As[128 * 64], Bs[128 * 64];   // 32 KB
  const int bid = blockIdx.x;                 // 1536 blocks
  const int xcd = bid & 7, idx = bid >> 3;
  const int bx = idx >> 3, by = xcd * 8 + (idx & 7);
  const int t = threadIdx.x, w = t >> 6, l = t & 63, lg = l >> 4, lr = l & 15;
  const int m0 = by * 128, n0 = bx * 128;
  const int wm = w >> 1, wn = w & 1;
  const int r8 = l >> 3, ch = l & 7;          // staging lane geometry
  f32x4 acc[4][4] = {};
  for (int kt = 0; kt < 16; ++kt) {
    __syncthreads();
#pragma unroll
    for (int c2 = 0; c2 < 4; ++c2) {
      const int c = w * 4 + c2;               // chunk 0..15 (8 rows x 128B)
      const int row = c * 8 + r8;             // 0..127
      const int sc = (ch ^ (row & 7)) * 8;    // pre-swizzled source col
      gload_lds16(xb + (size_t)(m0 + row) * 1024 + kt * 64 + sc, &As[c * 512]);
      gload_lds16(Wp + (size_t)(n0 + row) * 1024 + kt * 64 + sc, &Bs[c * 512]);
    }
    __syncthreads();
#pragma unroll
    for (int hk = 0; hk < 2; ++hk) {          // two K=32 halves of the 64-tile
      bf16x8 af[4], bfr[4];
#pragma unroll
      for (int mt = 0; mt < 4; ++mt) {
        const int row = wm * 64 + mt * 16 + lr;
        af[mt] = *(const bf16x8*)(&As[row * 64 + (((hk * 4 + lg) ^ (row & 7)) * 8)]);
      }
#pragma unroll
      for (int nt = 0; nt < 4; ++nt) {
        const int row = wn * 64 + nt * 16 + lr;
        bfr[nt] = *(const bf16x8*)(&Bs[row * 64 + (((hk * 4 + lg) ^ (row & 7)) * 8)]);
      }
#pragma unroll
      for (int mt = 0; mt < 4; ++mt)
#pragma unroll
        for (int nt = 0; nt < 4; ++nt)
          acc[mt][nt] = MFMA16(af[mt], bfr[nt], acc[mt][nt]);
    }
  }
  // epilogue: bias + relu -> bf16. proj uniform across the wave (16-aligned n-chunks).
#pragma unroll
  for (int nt = 0; nt < 4; ++nt) {
    const int n = n0 + wn * 64 + nt * 16 + lr;
    const float bias = bqkv[n];
    const int proj = n >> 10, h = (n >> 6) & 15, dk = n & 63;
#pragma unroll
    for (int mt = 0; mt < 4; ++mt) {
      const int mb = m0 + wm * 64 + mt * 16 + lg * 4;  // j-quad base, same b & 4-aligned s
      const int b = mb >> 10, s = mb & 1023;
      float vv[4];
#pragma unroll
      for (int j = 0; j < 4; ++j) {
        float a = acc[mt][nt][j] + bias;
        vv[j] = a > 0.f ? a : 0.f;
      }
      if (proj == 2) {
        u16x4 o; o[0] = f2bf(vv[0]); o[1] = f2bf(vv[1]); o[2] = f2bf(vv[2]); o[3] = f2bf(vv[3]);
        *(u16x4*)(vTo + ((size_t)(b * 16 + h) * 64 + dk) * 1024 + s) = o;
      } else {
        ushort* op = proj == 0 ? qo : ko;
#pragma unroll
        for (int j = 0; j < 4; ++j)
          op[((size_t)(b * 16 + h) * 1024 + s + j) * 64 + dk] = f2bf(vv[j]);
      }
    }
  }
}

// ---------------- fused attention (EXACT R16: 64-row q-tiles, 4 waves) ------
// 2048 blocks (XCD-swizzled); per 128-kv group: stage K,V to LDS (coalesced
// gload_lds, chunk-XOR source pre-swizzle); QK^T (swapped) 8 frags; 4 slices
// of 32 kv {exp->p_q + scores->s_st; lgkmcnt; NT full-128B-line flush; PV}.
__global__ __launch_bounds__(256) void attn_kernel(const ushort* __restrict__ qg, const ushort* __restrict__ kg,
                                                   const ushort* __restrict__ vT, float* __restrict__ att,
                                                   ushort* __restrict__ heads) {
  const int bid = blockIdx.x;                 // 2048
  const int swz = (bid & 7) * 256 + (bid >> 3);
  const int qt = swz & 15, bh = swz >> 4;
  const int t = threadIdx.x, w = t >> 6, l = t & 63;
  const int lg = l >> 4, lr = l & 15;
  __shared__ ushort Ks[128 * 64];         // 16 KB, chunk-swizzled rows
  __shared__ ushort Vs[64 * 128];         // 16 KB, chunk-swizzled rows
  __shared__ ushort p_q[4][16][40];       // 5 KB, P quarter (32 kv), reused
  __shared__ float s_st[4][16][40];       // 10 KB, score quarter (32 kv), reused

  const ushort* qb = qg + (size_t)bh * 65536;
  const ushort* kb = kg + (size_t)bh * 65536;
  const ushort* vb = vT + (size_t)bh * 65536;
  const int qrow0 = qt * 64 + w * 16;

  const bf16x8 qf0 = *(const bf16x8*)(qb + (qrow0 + lr) * 64 + lg * 8);
  const bf16x8 qf1 = *(const bf16x8*)(qb + (qrow0 + lr) * 64 + 32 + lg * 8);

  const int krow = l >> 3, kch = l & 7;    // K: 8 rows x 8 chunks(16B)
  const int vrow = l >> 4, vch = l & 15;   // V: 4 rows x 16 chunks(16B)
  const int frow = l >> 3, fcol = (l & 7) * 4;  // flush: 8 rows x 128B per instr

  const float C2 = 0.125f * 1.44269504f;   // 1/sqrt(64) in exp2 domain
  f32x4 oacc[4] = {};
  float lsum = 0.f;
  float* attw = att + ((size_t)bh * 1024 + qrow0) * 1024;

  for (int g = 0; g < 8; ++g) {
    const int kv0 = g * 128;
    __syncthreads();   // all waves done reading previous group's tiles
#pragma unroll
    for (int c2 = 0; c2 < 4; ++c2) {
      const int call = w * 4 + c2;
      const int r = call * 8 + krow;       // K local row 0..127
      gload_lds16(kb + (size_t)(kv0 + r) * 64 + ((kch ^ (r & 7)) * 8), &Ks[call * 512]);
      const int rv = call * 4 + vrow;      // V local row (dk) 0..63
      gload_lds16(vb + (size_t)rv * 1024 + kv0 + ((vch ^ (rv & 15)) * 8), &Vs[call * 512]);
    }
    __syncthreads();   // stage complete
    // QK^T from LDS: sf[f][j] = S[q=lr][kv = kv0 + f*16 + lg*4 + j]
    f32x4 sf[8];
#pragma unroll
    for (int f = 0; f < 8; ++f) {
      const int r = f * 16 + lr;
      const bf16x8 kf0 = *(const bf16x8*)(&Ks[r * 64 + ((lg ^ (r & 7)) * 8)]);
      const bf16x8 kf1 = *(const bf16x8*)(&Ks[r * 64 + (((4 + lg) ^ (r & 7)) * 8)]);
      f32x4 s = {};
      s = MFMA16(kf0, qf0, s);
      s = MFMA16(kf1, qf1, s);
      sf[f] = s;
    }
    // 4 slices of 32 kv: exp/pack + score-stage -> nt line flush + PV
#pragma unroll
    for (int s = 0; s < 4; ++s) {
#pragma unroll
      for (int fi = 0; fi < 2; ++fi) {
        const int f = 2 * s + fi;
        u16x4 pk;
#pragma unroll
        for (int j = 0; j < 4; ++j) {
          const float p = exp2f(sf[f][j] * C2);
          lsum += p;
          pk[j] = f2bf(p);
        }
        *(u16x4*)(&p_q[w][lr][fi * 16 + lg * 4]) = pk;
        *(f32x4*)(&s_st[w][lr][fi * 16 + lg * 4]) = sf[f];
      }
      // per-wave LDS region; DS ops wave-program-order; wait for writes
      asm volatile("s_waitcnt lgkmcnt(0)" ::: "memory");
      __builtin_amdgcn_sched_barrier(0);
      const bf16x8 pa = *(const bf16x8*)(&p_q[w][lr][lg * 8]);
      // flush this slice: 2 instrs x 8 rows x 128B fully-covered aligned lines
#pragma unroll
      for (int i = 0; i < 2; ++i) {
        const int r = i * 8 + frow;
        const f32x4 fv = *(const f32x4*)(&s_st[w][r][fcol]);
        __builtin_nontemporal_store(fv,
            (f32x4*)(attw + (size_t)r * 1024 + kv0 + s * 32 + fcol));
      }
      // PV for this slice (LDS/reg only -> store retire shadow)
#pragma unroll
      for (int nt = 0; nt < 4; ++nt) {
        const int r = nt * 16 + lr;
        const bf16x8 vf = *(const bf16x8*)(&Vs[r * 128 + (((s * 4 + lg) ^ lr) * 8)]);
        oacc[nt] = MFMA16(pa, vf, oacc[nt]);
      }
    }
  }
  // row sums: reduce lane partials across lg groups
  lsum += __shfl_xor(lsum, 16, 64);
  lsum += __shfl_xor(lsum, 32, 64);
  float rdiv[4];
#pragma unroll
  for (int j = 0; j < 4; ++j) rdiv[j] = 1.f / __shfl(lsum, lg * 4 + j, 16);
  const int b = bh >> 4, h = bh & 15;
#pragma unroll
  for (int nt = 0; nt < 4; ++nt)
#pragma unroll
    for (int j = 0; j < 4; ++j)
      __builtin_nontemporal_store(f2bf(oacc[nt][j] * rdiv[j]),
          heads + (size_t)(b * 1024 + qrow0 + lg * 4 + j) * 1024 + h * 64 + nt * 16 + lr);
}

// ---------------- output GEMM: z_out = relu(heads @ Wo + bo) ----------------
// 512 blocks x 16-row m-tiles; 4 waves = 4-way K-split (256 K each); LDS
// reduce; wave 0 epilogue.
__global__ __launch_bounds__(256) void gemm_out(const ushort* __restrict__ z, const ushort* __restrict__ Wop,
                                                const float* __restrict__ bo, float* __restrict__ out) {
  __shared__ float red[4][16][64];
  const int t = threadIdx.x, w = t >> 6, l = t & 63, lg = l >> 4, lr = l & 15;
  const int m0 = blockIdx.x * 16;
  f32x4 acc[4] = {};
  for (int kk = w * 8; kk < w * 8 + 8; ++kk) {
    bf16x8 af = *(const bf16x8*)(z + (size_t)(m0 + lr) * 1024 + kk * 32 + lg * 8);
#pragma unroll
    for (int nt = 0; nt < 4; ++nt) {
      bf16x8 bfr = *(const bf16x8*)(Wop + (size_t)(nt * 16 + lr) * 1024 + kk * 32 + lg * 8);
      acc[nt] = MFMA16(af, bfr, acc[nt]);
    }
  }
  if (w) {
#pragma unroll
    for (int nt = 0; nt < 4; ++nt)
#pragma unroll
      for (int j = 0; j < 4; ++j) red[w][lg * 4 + j][nt * 16 + lr] = acc[nt][j];
  }
  __syncthreads();
  if (w == 0) {
#pragma unroll
    for (int nt = 0; nt < 4; ++nt) {
      const int n = nt * 16 + lr;
      const float bb = bo[n];
#pragma unroll
      for (int j = 0; j < 4; ++j) {
        const int m = lg * 4 + j;
        float vv = acc[nt][j] + red[1][m][n] + red[2][m][n] + red[3][m][n] + bb;
        out[(size_t)(m0 + m) * 64 + n] = vv > 0.f ? vv : 0.f;
      }
    }
  }
}

// ---------------------------------------------------------------------------
extern "C" void kernel_launch(void* const* d_in, const int* in_sizes, int n_in,
                              void* d_out, int out_size, void* d_ws, size_t ws_size,
                              hipStream_t stream) {
  const float* x  = (const float*)d_in[0];
  const float* Wq = (const float*)d_in[1];
  const float* bq = (const float*)d_in[2];
  const float* Wk = (const float*)d_in[3];
  const float* bk = (const float*)d_in[4];
  const float* Wv = (const float*)d_in[5];
  const float* bv = (const float*)d_in[6];
  const float* Wo = (const float*)d_in[7];
  const float* bo = (const float*)d_in[8];
  float* out = (float*)d_out;            // z_out: 8*1024*64 = 524288 f32
  float* att = out + 524288;             // att:   8*16*1024*1024 f32

  // workspace layout (~92 MB)
  char* ws = (char*)d_ws;
  size_t off = 0;
  ushort* xb  = (ushort*)(ws + off); off += (size_t)8192 * 1024 * 2;
  ushort* Wp  = (ushort*)(ws + off); off += (size_t)3072 * 1024 * 2;
  ushort* Wop = (ushort*)(ws + off); off += (size_t)64 * 1024 * 2;
  float* bqkv = (float*)(ws + off);  off += (size_t)3072 * 4;
  ushort* q   = (ushort*)(ws + off); off += (size_t)128 * 1024 * 64 * 2;
  ushort* k   = (ushort*)(ws + off); off += (size_t)128 * 1024 * 64 * 2;
  ushort* vT  = (ushort*)(ws + off); off += (size_t)128 * 64 * 1024 * 2;
  ushort* hds = (ushort*)(ws + off); off += (size_t)8192 * 1024 * 2;
  (void)ws_size; (void)in_sizes; (void)n_in; (void)out_size;

  pack_all<<<dim3(9229), dim3(256), 0, stream>>>(x, Wq, Wk, Wv, Wo, bq, bk, bv,
                                                 xb, Wp, Wop, bqkv);
  gemm_qkv<<<dim3(1536), dim3(256), 0, stream>>>(xb, Wp, bqkv, q, k, vT);
  attn_kernel<<<dim3(2048), dim3(256), 0, stream>>>(q, k, vT, att, hds);
  gemm_out<<<dim3(512), dim3(256), 0, stream>>>(hds, Wop, bo, out);
}